// Round 3
// baseline (75005.499 us; speedup 1.0000x reference)
//
#include <hip/hip_runtime.h>

#define TT   512
#define NBOX 30
#define HDIM 512
#define M1 (TT*31)     // 15872
#define N1 HDIM        // 512
#define K1 4096
#define M2 (TT*NBOX)   // 15360
#define N2 (3*HDIM)    // 1536
#define K2 (2*HDIM)    // 1024
#define NWG 256
#define FSTR 32        // flag stride in u32 (128 B line per WG flag)

__device__ __forceinline__ float4 ld4(const float* p) { return *(const float4*)p; }
__device__ __forceinline__ float dot4(float4 a, float4 b) { return a.x*b.x + a.y*b.y + a.z*b.z + a.w*b.w; }
__device__ __forceinline__ float sigf(float x) { return 1.f / (1.f + __expf(-x)); }
__device__ __forceinline__ float thf(float x)  { return 1.f - 2.f / (1.f + __expf(2.f*x)); }

// ---------------------------------------------------------------------------
// GEMM 1: xv = relu(flow @ W_phi + b_phi)   (unchanged — known correct)
// ---------------------------------------------------------------------------
__global__ __launch_bounds__(256) void gemm_phi(const float* __restrict__ A,
                                                const float* __restrict__ B,
                                                const float* __restrict__ bias,
                                                float* __restrict__ C) {
    __shared__ float As[16][68];
    __shared__ float Bs[16][68];
    const int tid = threadIdx.x;
    const int m0 = blockIdx.x * 64;
    const int n0 = blockIdx.y * 64;
    const int am = tid >> 2, ak = (tid & 3) << 2;
    const int bk = tid >> 4, bn = (tid & 15) << 2;
    const int ty = tid >> 4, tx = tid & 15;
    float acc[4][4] = {};
    for (int k0 = 0; k0 < K1; k0 += 16) {
        const float4 av = *(const float4*)&A[(size_t)(m0 + am) * K1 + k0 + ak];
        const float4 bv = *(const float4*)&B[(size_t)(k0 + bk) * N1 + n0 + bn];
        __syncthreads();
        As[ak + 0][am] = av.x; As[ak + 1][am] = av.y; As[ak + 2][am] = av.z; As[ak + 3][am] = av.w;
        *(float4*)&Bs[bk][bn] = bv;
        __syncthreads();
#pragma unroll
        for (int kk = 0; kk < 16; ++kk) {
            const float4 a = *(const float4*)&As[kk][ty << 2];
            const float4 b = *(const float4*)&Bs[kk][tx << 2];
            const float ar[4] = {a.x, a.y, a.z, a.w};
            const float br[4] = {b.x, b.y, b.z, b.w};
#pragma unroll
            for (int i = 0; i < 4; ++i)
#pragma unroll
                for (int j = 0; j < 4; ++j) acc[i][j] = fmaf(ar[i], br[j], acc[i][j]);
        }
    }
    const float4 bsv = *(const float4*)&bias[n0 + (tx << 2)];
    const float bb[4] = {bsv.x, bsv.y, bsv.z, bsv.w};
#pragma unroll
    for (int i = 0; i < 4; ++i) {
        const int m = m0 + (ty << 2) + i;
        float4 o;
        o.x = fmaxf(acc[i][0] + bb[0], 0.f);
        o.y = fmaxf(acc[i][1] + bb[1], 0.f);
        o.z = fmaxf(acc[i][2] + bb[2], 0.f);
        o.w = fmaxf(acc[i][3] + bb[3], 0.f);
        *(float4*)&C[(size_t)m * N1 + n0 + (tx << 2)] = o;
    }
}

// ---------------------------------------------------------------------------
// GEMM 2: gi0 = x_t @ Wih0^T + bih0  (unchanged)
// ---------------------------------------------------------------------------
__global__ __launch_bounds__(256) void gemm_gi0(const float* __restrict__ xv,
                                                const float* __restrict__ Wih0,
                                                const float* __restrict__ bih0,
                                                float* __restrict__ C) {
    __shared__ float As[16][68];
    __shared__ float Bs[16][68];
    const int tid = threadIdx.x;
    const int m0 = blockIdx.x * 64;
    const int n0 = blockIdx.y * 64;
    const int am = tid >> 2, ak = (tid & 3) << 2;
    const int bn_ = tid >> 2, bkq = (tid & 3) << 2;
    const int ty = tid >> 4, tx = tid & 15;
    const int r = m0 + am;
    const int t = r / 30;
    const int j = r - t * 30;
    const float* rowTrk = xv + ((size_t)(t * 31 + 1 + j) << 9);
    const float* rowImg = xv + ((size_t)(t * 31) << 9);
    float acc[4][4] = {};
    for (int k0 = 0; k0 < K2; k0 += 16) {
        const int kg = k0 + ak;
        const float4 av = (kg < 512) ? *(const float4*)&rowTrk[kg]
                                     : *(const float4*)&rowImg[kg - 512];
        const float4 wv = *(const float4*)&Wih0[(size_t)(n0 + bn_) * K2 + k0 + bkq];
        __syncthreads();
        As[ak + 0][am] = av.x; As[ak + 1][am] = av.y; As[ak + 2][am] = av.z; As[ak + 3][am] = av.w;
        Bs[bkq + 0][bn_] = wv.x; Bs[bkq + 1][bn_] = wv.y; Bs[bkq + 2][bn_] = wv.z; Bs[bkq + 3][bn_] = wv.w;
        __syncthreads();
#pragma unroll
        for (int kk = 0; kk < 16; ++kk) {
            const float4 a = *(const float4*)&As[kk][ty << 2];
            const float4 b = *(const float4*)&Bs[kk][tx << 2];
            const float ar[4] = {a.x, a.y, a.z, a.w};
            const float br[4] = {b.x, b.y, b.z, b.w};
#pragma unroll
            for (int i = 0; i < 4; ++i)
#pragma unroll
                for (int jq = 0; jq < 4; ++jq) acc[i][jq] = fmaf(ar[i], br[jq], acc[i][jq]);
        }
    }
    const float4 bsv = *(const float4*)&bih0[n0 + (tx << 2)];
    const float bb[4] = {bsv.x, bsv.y, bsv.z, bsv.w};
#pragma unroll
    for (int i = 0; i < 4; ++i) {
        const int m = m0 + (ty << 2) + i;
        float4 o;
        o.x = acc[i][0] + bb[0];
        o.y = acc[i][1] + bb[1];
        o.z = acc[i][2] + bb[2];
        o.w = acc[i][3] + bb[3];
        *(float4*)&C[(size_t)m * N2 + n0 + (tx << 2)] = o;
    }
}

// ---------------------------------------------------------------------------
__global__ __launch_bounds__(256) void gic_kernel(const int* __restrict__ y,
                                                  const float* __restrict__ Wihc,
                                                  const float* __restrict__ bihc,
                                                  float* __restrict__ gic) {
    const int idx = blockIdx.x * 256 + threadIdx.x;
    if (idx >= M2 * 96) return;
    const int g = idx % 96;
    const int tj = idx / 96;
    const int* yb = y + (size_t)tj * 6;
    const float c0 = (float)yb[1] * (1.f / 1080.f);
    const float c1 = (float)yb[2] * (1.f / 720.f);
    const float c2 = (float)yb[3] * (1.f / 1080.f);
    const float c3 = (float)yb[4] * (1.f / 720.f);
    gic[idx] = bihc[g] + c0 * Wihc[g * 4 + 0] + c1 * Wihc[g * 4 + 1]
                       + c2 * Wihc[g * 4 + 2] + c3 * Wihc[g * 4 + 3];
}

__global__ void transpose_w1(const float* __restrict__ W1, float* __restrict__ W1T) {
    const int idx = blockIdx.x * 256 + threadIdx.x;
    if (idx >= 544 * 256) return;
    const int c = idx % 544, u = idx / 544;
    W1T[idx] = W1[c * 256 + u];
}

// zero the whole flag array (256 flags x 128B lines); re-run every launch
__global__ void init_k(unsigned* flags) {
    const int tid = threadIdx.x;
    for (int i = tid; i < NWG * FSTR; i += 256) flags[i] = 0u;
}

// ---------------------------------------------------------------------------
// Grid barrier: per-WG arrival flag on its own 128B line (release STORE, no
// RMW); thread i of every WG polls WG i's flag. No shared hot line.
// ---------------------------------------------------------------------------
__device__ __forceinline__ void gbar(unsigned* flags, unsigned ep) {
    __syncthreads();
    if (threadIdx.x == 0) {
        __threadfence();
        __hip_atomic_store(&flags[(unsigned)blockIdx.x * FSTR], ep,
                           __ATOMIC_RELEASE, __HIP_MEMORY_SCOPE_AGENT);
    }
    const unsigned fi = (unsigned)threadIdx.x * FSTR;
    while (__hip_atomic_load(&flags[fi], __ATOMIC_ACQUIRE, __HIP_MEMORY_SCOPE_AGENT) < ep) {
        __builtin_amdgcn_s_sleep(1);
    }
    __threadfence();
    __syncthreads();
}

__device__ void softmax30(const float* raw, const int* yt, float* outp) {
    float s[NBOX];
    float mx = -1e30f;
    for (int j = 0; j < NBOX; ++j) {
        s[j] = raw[j];
        if (yt[j * 6] != 0 && s[j] > mx) mx = s[j];
    }
    float sum = 0.f;
    for (int j = 0; j < NBOX; ++j) {
        s[j] = (yt[j * 6] != 0) ? __expf(s[j] - mx) : 0.f;
        sum += s[j];
    }
    const float inv = 1.f / fmaxf(sum, 1e-9f);
    for (int j = 0; j < NBOX; ++j) outp[j] = s[j] * inv;
}

struct PArgs {
    const float *gi0, *gic;
    const float *Whh0, *Wih1, *Whh1, *Whhc;
    const float *bhh0, *bih1, *bhh1, *bhhc;
    const float *W1T, *b1, *W2, *b2, *wa, *wac;
    const int *y;
    float *Z0, *Z1, *h0, *h1, *hc, *s0raw, *s1raw, *partials, *out;
    unsigned *flags;
};

__global__ __launch_bounds__(256, 1) void persist(PArgs A) {
    __shared__ float gi_s[NBOX][6];
    __shared__ float sA[NBOX];
    __shared__ float red[256];
    __shared__ float chc[NBOX][32];
    __shared__ float cZc[NBOX][96];
    __shared__ float cscr[NBOX];
    __shared__ float csca[NBOX];

    const int w = blockIdx.x;
    const int tid = threadIdx.x;
    unsigned ep = 0;
    float lossSum = 0.f;

    // ---- INIT: h0_n(0), parity 0
    if (tid < 60) {
        const int idx = w * 60 + tid;
        const int j = idx >> 9, c = idx & 511;
        const float* gp = A.gi0 + j * 1536;
        const float r = sigf(gp[c] + A.bhh0[c]);
        const float z = sigf(gp[512 + c] + A.bhh0[512 + c]);
        const float n = thf(gp[1024 + c] + r * A.bhh0[1024 + c]);
        A.h0[idx] = (1.f - z) * n;
    }
    gbar(A.flags, ++ep);

    for (int t = 0; t < TT; ++t) {
        const int parC = t & 1, parP = parC ^ 1;
        // ================= P(t) =================
        {
            const float* h0c = A.h0 + parC * 15360;
            if (tid == 0) {
                if (t == 0) { for (int j = 0; j < NBOX; ++j) sA[j] = 0.f; }
                else softmax30(A.s1raw, A.y + (size_t)(t - 1) * 180, sA);
                if (w == NWG - 1) {
                    if (t == 0) { for (int j = 0; j < NBOX; ++j) csca[j] = 0.f; }
                    else softmax30(cscr, A.y + (size_t)(t - 1) * 180, csca);
                }
            }
            float z1r = 0.f, z1z = 0.f, z1n = 0.f, h1p = 0.f;
            int cj = 0, cc = 0;
            if (tid < 60) {
                cj = tid >> 1; cc = 2 * w + (tid & 1);
                z1r = A.Z1[cj * 1536 + cc];
                z1z = A.Z1[cj * 1536 + 512 + cc];
                z1n = A.Z1[cj * 1536 + 1024 + cc];
                h1p = A.h1[parP * 15360 + cj * 512 + cc];
            }
            if (tid < 240 && (tid & 7) < 6) {
                const int j = tid >> 3, q = tid & 7;
                const float* hrow = h0c + j * 512;
                const float* W; int colA, colB;
                if (q < 3) { W = A.Whh0; colA = 6 * w + 2 * q; colB = colA + 1; }
                else {
                    W = A.Wih1;
                    const int G[6] = {2*w, 512 + 2*w, 1024 + 2*w, 2*w + 1, 513 + 2*w, 1025 + 2*w};
                    colA = G[(q - 3) * 2]; colB = G[(q - 3) * 2 + 1];
                }
                const float* wA = W + (size_t)colA * 512;
                const float* wB = W + (size_t)colB * 512;
                float a0 = 0.f, a1 = 0.f;
#pragma unroll 4
                for (int k = 0; k < 512; k += 4) {
                    const float4 h4 = ld4(hrow + k);
                    a0 += dot4(h4, ld4(wA + k));
                    a1 += dot4(h4, ld4(wB + k));
                }
                if (q < 3) { A.Z0[j * 1536 + colA] = a0; A.Z0[j * 1536 + colB] = a1; }
                else {
                    const int g = (q - 3) * 2;
                    gi_s[j][g]     = a0 + A.bih1[colA];
                    gi_s[j][g + 1] = a1 + A.bih1[colB];
                }
            }
            __syncthreads();
            if (tid < 60) {
                const float s = sA[cj];
                const int ci = tid & 1;
                const float r = sigf(gi_s[cj][ci * 3 + 0] + s * z1r + A.bhh1[cc]);
                const float z = sigf(gi_s[cj][ci * 3 + 1] + s * z1z + A.bhh1[512 + cc]);
                const float n = thf (gi_s[cj][ci * 3 + 2] + r * (s * z1n + A.bhh1[1024 + cc]));
                A.h1[parC * 15360 + cj * 512 + cc] = (1.f - z) * n + z * (s * h1p);
            }
            if (w >= 224 && w < 254) {
                const int jd = w - 224;
                const float* hrow = h0c + jd * 512;
                red[tid] = thf(hrow[tid]) * A.wa[tid] + thf(hrow[tid + 256]) * A.wa[tid + 256];
                __syncthreads();
                for (int sft = 128; sft > 0; sft >>= 1) {
                    if (tid < sft) red[tid] += red[tid + sft];
                    __syncthreads();
                }
                if (tid == 0) A.s0raw[jd] = red[0];
            }
            if (w == NWG - 1) {
                for (int idx = tid; idx < 960; idx += 256) {
                    const int j = idx >> 5, c = idx & 31;
                    const float s = csca[j];
                    const float* gp = A.gic + (size_t)t * 2880 + j * 96;
                    const float r = sigf(gp[c]      + s * cZc[j][c]      + A.bhhc[c]);
                    const float z = sigf(gp[32 + c] + s * cZc[j][32 + c] + A.bhhc[32 + c]);
                    const float n = thf (gp[64 + c] + r * (s * cZc[j][64 + c] + A.bhhc[64 + c]));
                    const float hn = (1.f - z) * n + z * (s * chc[j][c]);
                    chc[j][c] = hn;
                    A.hc[j * 32 + c] = hn;
                }
                __syncthreads();
                for (int idx = tid; idx < 2880; idx += 256) {
                    const int j = idx / 96, g = idx - j * 96;
                    const float* wr = A.Whhc + g * 32;
                    float a = 0.f;
#pragma unroll
                    for (int c2 = 0; c2 < 32; c2 += 4) a += dot4(ld4(&chc[j][c2]), ld4(wr + c2));
                    cZc[j][g] = a;
                }
                if (tid < 240) {
                    const int j = tid >> 3, seg = tid & 7;
                    float p = 0.f;
                    for (int c2 = seg * 4; c2 < seg * 4 + 4; ++c2) p += thf(chc[j][c2]) * A.wac[c2];
                    p += __shfl_down(p, 4, 8);
                    p += __shfl_down(p, 2, 8);
                    p += __shfl_down(p, 1, 8);
                    if (seg == 0) cscr[j] = p;
                }
            }
        }
        gbar(A.flags, ++ep);
        // ================= Q(t) =================
        {
            const float* h1c = A.h1 + parC * 15360;
            const float* h0c = A.h0 + parC * 15360;
            if (tid == 0) softmax30(A.s0raw, A.y + (size_t)t * 180, sA);
            float g_r = 0.f, g_z = 0.f, g_n = 0.f, z0r = 0.f, z0z = 0.f, z0n = 0.f, h0p = 0.f;
            int cj2 = 0, cc2 = 0;
            if (tid < 60 && t < TT - 1) {
                const int idx = w * 60 + tid;
                cj2 = idx >> 9; cc2 = idx & 511;
                const float* gp = A.gi0 + (size_t)(t + 1) * 46080 + cj2 * 1536;
                g_r = gp[cc2]; g_z = gp[512 + cc2]; g_n = gp[1024 + cc2];
                z0r = A.Z0[cj2 * 1536 + cc2];
                z0z = A.Z0[cj2 * 1536 + 512 + cc2];
                z0n = A.Z0[cj2 * 1536 + 1024 + cc2];
                h0p = h0c[idx];
            }
            if (w < 192) {
                if (tid < 240 && (tid & 7) < 4) {
                    const int j = tid >> 3, q = tid & 7;
                    const int colA = 8 * w + 2 * q, colB = colA + 1;
                    const float* hrow = h1c + j * 512;
                    const float* wA = A.Whh1 + (size_t)colA * 512;
                    const float* wB = A.Whh1 + (size_t)colB * 512;
                    float a0 = 0.f, a1 = 0.f;
#pragma unroll 4
                    for (int k = 0; k < 512; k += 4) {
                        const float4 h4 = ld4(hrow + k);
                        a0 += dot4(h4, ld4(wA + k));
                        a1 += dot4(h4, ld4(wB + k));
                    }
                    A.Z1[j * 1536 + colA] = a0;
                    A.Z1[j * 1536 + colB] = a1;
                }
            } else if (w < 224) {
                const int b = w - 192;
                if (tid < 240) {
                    const int j = tid >> 3, u = tid & 7, ug = b * 8 + u;
                    const float* w1r = A.W1T + (size_t)ug * 544;
                    const float* hrow = h1c + j * 512;
                    float acc = A.b1[ug];
#pragma unroll 4
                    for (int c2 = 0; c2 < 512; c2 += 4) acc += dot4(ld4(hrow + c2), ld4(w1r + c2));
                    const float* hcr = A.hc + j * 32;
#pragma unroll
                    for (int c2 = 0; c2 < 32; c2 += 4) acc += dot4(ld4(hcr + c2), ld4(w1r + 512 + c2));
                    const float uu = fmaxf(acc, 0.f);
                    float p0 = uu * A.W2[2 * ug], p1 = uu * A.W2[2 * ug + 1];
                    p0 += __shfl_down(p0, 4, 8); p0 += __shfl_down(p0, 2, 8); p0 += __shfl_down(p0, 1, 8);
                    p1 += __shfl_down(p1, 4, 8); p1 += __shfl_down(p1, 2, 8); p1 += __shfl_down(p1, 1, 8);
                    if (u == 0) {
                        float* pp = A.partials + (t & 1) * 1920 + b * 60 + j * 2;
                        pp[0] = p0; pp[1] = p1;
                    }
                }
            } else if (w < 254) {
                const int jd = w - 224;
                const float* hrow = h1c + jd * 512;
                red[tid] = thf(hrow[tid]) * A.wa[tid] + thf(hrow[tid + 256]) * A.wa[tid + 256];
                __syncthreads();
                for (int sft = 128; sft > 0; sft >>= 1) {
                    if (tid < sft) red[tid] += red[tid + sft];
                    __syncthreads();
                }
                if (tid == 0) A.s1raw[jd] = red[0];
            } else if (w == 254 && t > 0) {
                const int tt = t - 1, par = tt & 1;
                if (tid < 30) {
                    float o0 = A.b2[0], o1 = A.b2[1];
                    const float* pp = A.partials + par * 1920;
                    for (int b2i = 0; b2i < 32; ++b2i) {
                        o0 += pp[b2i * 60 + tid * 2];
                        o1 += pp[b2i * 60 + tid * 2 + 1];
                    }
                    const int* yb = A.y + (size_t)tt * 180 + tid * 6;
                    const float pm = (yb[0] != 0) ? 1.f : 0.f;
                    const float m = fmaxf(o0, o1);
                    const float lse = m + __logf(__expf(o0 - m) + __expf(o1 - m));
                    const float lt = (yb[5] == 0) ? o0 : o1;
                    red[tid] = pm * (lse - lt);
                    A.out[1 + (size_t)tt * 60 + tid * 2]     = o0 * pm;
                    A.out[1 + (size_t)tt * 60 + tid * 2 + 1] = o1 * pm;
                }
                __syncthreads();
                if (tid == 0) { float s = 0.f; for (int j = 0; j < NBOX; ++j) s += red[j]; lossSum += s; }
            }
            __syncthreads();
            if (tid < 60 && t < TT - 1) {
                const float s = sA[cj2];
                const float r = sigf(g_r + s * z0r + A.bhh0[cc2]);
                const float z = sigf(g_z + s * z0z + A.bhh0[512 + cc2]);
                const float n = thf (g_n + r * (s * z0n + A.bhh0[1024 + cc2]));
                A.h0[parP * 15360 + cj2 * 512 + cc2] = (1.f - z) * n + z * (s * h0p);
            }
        }
        gbar(A.flags, ++ep);
    }
    if (w == 254) {
        const int tt = TT - 1, par = tt & 1;
        if (tid < 30) {
            float o0 = A.b2[0], o1 = A.b2[1];
            const float* pp = A.partials + par * 1920;
            for (int b2i = 0; b2i < 32; ++b2i) {
                o0 += pp[b2i * 60 + tid * 2];
                o1 += pp[b2i * 60 + tid * 2 + 1];
            }
            const int* yb = A.y + (size_t)tt * 180 + tid * 6;
            const float pm = (yb[0] != 0) ? 1.f : 0.f;
            const float m = fmaxf(o0, o1);
            const float lse = m + __logf(__expf(o0 - m) + __expf(o1 - m));
            const float lt = (yb[5] == 0) ? o0 : o1;
            red[tid] = pm * (lse - lt);
            A.out[1 + (size_t)tt * 60 + tid * 2]     = o0 * pm;
            A.out[1 + (size_t)tt * 60 + tid * 2 + 1] = o1 * pm;
        }
        __syncthreads();
        if (tid == 0) {
            float s = 0.f;
            for (int j = 0; j < NBOX; ++j) s += red[j];
            A.out[0] = lossSum + s;
        }
    }
}

// ---------------------------------------------------------------------------
extern "C" void kernel_launch(void* const* d_in, const int* in_sizes, int n_in,
                              void* d_out, int out_size, void* d_ws, size_t ws_size,
                              hipStream_t stream) {
    (void)in_sizes; (void)n_in; (void)out_size; (void)ws_size;
    const int*   y     = (const int*)d_in[1];
    const float* flow  = (const float*)d_in[2];
    const float* W_phi = (const float*)d_in[3];
    const float* b_phi = (const float*)d_in[4];
    const float* Wih0  = (const float*)d_in[5];
    const float* Whh0  = (const float*)d_in[6];
    const float* bih0  = (const float*)d_in[7];
    const float* bhh0  = (const float*)d_in[8];
    const float* Wih1  = (const float*)d_in[9];
    const float* Whh1  = (const float*)d_in[10];
    const float* bih1  = (const float*)d_in[11];
    const float* bhh1  = (const float*)d_in[12];
    const float* Wihc  = (const float*)d_in[13];
    const float* Whhc  = (const float*)d_in[14];
    const float* bihc  = (const float*)d_in[15];
    const float* bhhc  = (const float*)d_in[16];
    const float* W1    = (const float*)d_in[17];
    const float* b1    = (const float*)d_in[18];
    const float* W2    = (const float*)d_in[19];
    const float* b2    = (const float*)d_in[20];
    const float* wa    = (const float*)d_in[21];
    const float* wac   = (const float*)d_in[22];
    float* out = (float*)d_out;

    float* ws = (float*)d_ws;
    float* xv   = ws;  ws += (size_t)M1 * N1;
    float* gi0  = ws;  ws += (size_t)M2 * N2;
    float* gic  = ws;  ws += (size_t)M2 * 96;
    float* W1T  = ws;  ws += 544 * 256;
    float* Z0   = ws;  ws += NBOX * 1536;
    float* Z1   = ws;  ws += NBOX * 1536;
    float* h0   = ws;  ws += 2 * NBOX * 512;
    float* h1   = ws;  ws += 2 * NBOX * 512;
    float* hc   = ws;  ws += NBOX * 32;
    float* s0raw = ws; ws += 32;
    float* s1raw = ws; ws += 32;
    float* partials = ws; ws += 2 * 32 * NBOX * 2;
    unsigned* flags = (unsigned*)ws; ws += NWG * FSTR;

    hipLaunchKernelGGL(init_k, dim3(1), dim3(256), 0, stream, flags);
    hipLaunchKernelGGL(gemm_phi, dim3(M1 / 64, N1 / 64), dim3(256), 0, stream, flow, W_phi, b_phi, xv);
    hipLaunchKernelGGL(gemm_gi0, dim3(M2 / 64, N2 / 64), dim3(256), 0, stream, xv, Wih0, bih0, gi0);
    hipLaunchKernelGGL(gic_kernel, dim3((M2 * 96 + 255) / 256), dim3(256), 0, stream, y, Wihc, bihc, gic);
    hipLaunchKernelGGL(transpose_w1, dim3((544 * 256 + 255) / 256), dim3(256), 0, stream, W1, W1T);

    PArgs A;
    A.gi0 = gi0; A.gic = gic;
    A.Whh0 = Whh0; A.Wih1 = Wih1; A.Whh1 = Whh1; A.Whhc = Whhc;
    A.bhh0 = bhh0; A.bih1 = bih1; A.bhh1 = bhh1; A.bhhc = bhhc;
    A.W1T = W1T; A.b1 = b1; A.W2 = W2; A.b2 = b2; A.wa = wa; A.wac = wac;
    A.y = y;
    A.Z0 = Z0; A.Z1 = Z1; A.h0 = h0; A.h1 = h1; A.hc = hc;
    A.s0raw = s0raw; A.s1raw = s1raw; A.partials = partials; A.out = out;
    A.flags = flags;
    hipLaunchKernelGGL(persist, dim3(NWG), dim3(256), 0, stream, A);
}